// Round 16
// baseline (3465.833 us; speedup 1.0000x reference)
//
#include <hip/hip_runtime.h>

typedef unsigned short u16;
typedef unsigned int u32;
typedef __attribute__((ext_vector_type(8))) short short8;
typedef __attribute__((ext_vector_type(4))) float f32x4;

#define NN 10000
#define NE 160000
#define ET 170000
#define FI 50
#define DB 1024
#define NT 121

static __device__ __forceinline__ float bf2f(u16 b) { return __uint_as_float(((u32)b) << 16); }
static __device__ __forceinline__ u16 f2bf(float f) {
  u32 u = __float_as_uint(f);
  u += 0x7FFFu + ((u >> 16) & 1u);
  return (u16)(u >> 16);
}
static __device__ __forceinline__ float eluf(float x) { return x > 0.f ? x : __expf(x) - 1.f; }
static __device__ __forceinline__ float lrelu(float x) { return x > 0.f ? x : 0.2f * x; }

__device__ __forceinline__ void gload16(const void* g, void* l) {
  __builtin_amdgcn_global_load_lds((const __attribute__((address_space(1))) u32*)g,
                                   (__attribute__((address_space(3))) u32*)l, 16, 0, 0);
}

// ---- edge dtype detection: int64 data has all-zero odd 32-bit words ----
__global__ __launch_bounds__(256) void k_detect(const int* __restrict__ ei, int* flag) {
  int any = 0;
  for (int i = threadIdx.x; i < NE; i += 256) any |= ei[2 * i + 1];
  if (any) flag[0] = 1;  // 1 => int32 layout
}

__global__ __launch_bounds__(256) void k_deg(const int* __restrict__ ei, const int* __restrict__ flag,
                                             int* deg) {
  int e = blockIdx.x * 256 + threadIdx.x;
  if (e >= ET) return;
  int is32 = flag[0];
  int d = (e < NE) ? (is32 ? ei[NE + e] : ei[2 * (NE + e)]) : (e - NE);
  atomicAdd(&deg[d], 1);
}

__global__ __launch_bounds__(256) void k_scan(const int* __restrict__ deg, int* __restrict__ rowptr) {
  __shared__ int ps[256];
  int tid = threadIdx.x;
  int s = 0;
  for (int i = 0; i < 40; i++) { int idx = tid * 40 + i; if (idx < NN) s += deg[idx]; }
  ps[tid] = s;
  __syncthreads();
  if (tid == 0) {
    int run = 0;
    for (int i = 0; i < 256; i++) { int v = ps[i]; ps[i] = run; run += v; }
    rowptr[NN] = run;
  }
  __syncthreads();
  int run = ps[tid];
  for (int i = 0; i < 40; i++) {
    int idx = tid * 40 + i;
    if (idx < NN) { rowptr[idx] = run; run += deg[idx]; }
  }
}

__global__ __launch_bounds__(256) void k_fill(const int* __restrict__ ei, const int* __restrict__ flag,
                                              const int* __restrict__ rowptr, int* fill, int* csr) {
  int e = blockIdx.x * 256 + threadIdx.x;
  if (e >= ET) return;
  int is32 = flag[0];
  int s, d;
  if (e < NE) { s = is32 ? ei[e] : ei[2 * e]; d = is32 ? ei[NE + e] : ei[2 * (NE + e)]; }
  else { s = d = e - NE; }
  int pos = atomicAdd(&fill[d], 1);
  csr[rowptr[d] + pos] = s;
}

// ---- body: h_body = x@W_body, xfc = x@Wfc (f32 compute, bf16 store, K=50) ----
__global__ __launch_bounds__(256) void k_body_gemm(const float* __restrict__ x, const float* __restrict__ Wb,
                                                   const float* __restrict__ Wfc,
                                                   u16* __restrict__ h_body, u16* __restrict__ xfc) {
  __shared__ float xs[32][52];
  int tid = threadIdx.x;
  int m0 = blockIdx.x * 32;
  for (int i = tid; i < 32 * FI; i += 256) {
    int r = i / FI, c = i - r * FI;
    int row = m0 + r; if (row > NN - 1) row = NN - 1;
    xs[r][c] = x[(size_t)row * FI + c];
  }
  __syncthreads();
  int col = blockIdx.y * 256 + tid;
  const float* Wp; u16* op;
  if (col < DB) { Wp = Wb + col; op = h_body + col; }
  else { Wp = Wfc + (col - DB); op = xfc + (col - DB); }
  float acc[32];
  #pragma unroll
  for (int m = 0; m < 32; m++) acc[m] = 0.f;
  for (int k = 0; k < FI; k++) {
    float wv = Wp[(size_t)k * DB];
    #pragma unroll
    for (int m = 0; m < 32; m++) acc[m] += xs[m][k] * wv;
  }
  #pragma unroll
  for (int m = 0; m < 32; m++) {
    int row = m0 + m;
    if (row < NN) op[(size_t)row * DB] = f2bf(acc[m]);
  }
}

__global__ __launch_bounds__(64) void k_body_al(const u16* __restrict__ h_body, const float* __restrict__ as,
                                                const float* __restrict__ ad, float* __restrict__ al) {
  int n = blockIdx.x, l = threadIdx.x;
  const u16* hr = h_body + (size_t)n * DB + l * 16;
  const float* ap = as + l * 16;
  const float* dp = ad + l * 16;
  float ss = 0.f, sd = 0.f;
  #pragma unroll
  for (int i = 0; i < 16; i++) { float hv = bf2f(hr[i]); ss += hv * ap[i]; sd += hv * dp[i]; }
  #pragma unroll
  for (int o = 1; o < 16; o <<= 1) { ss += __shfl_xor(ss, o); sd += __shfl_xor(sd, o); }
  if ((l & 15) == 0) { int h = l >> 4; al[(size_t)n * 8 + h] = ss; al[(size_t)n * 8 + 4 + h] = sd; }
}

__global__ __launch_bounds__(256) void k_body_agg(const u16* __restrict__ h_body, const u16* __restrict__ xfc,
                                                  const float* __restrict__ al, const int* __restrict__ rowptr,
                                                  const int* __restrict__ csr, const float* __restrict__ bb,
                                                  const float* __restrict__ bfc, u16* __restrict__ x1b) {
  __shared__ float wl[256];
  __shared__ int sl[64];
  int n = blockIdx.x, tid = threadIdx.x;
  int c0 = tid * 4, h = tid >> 6;
  float acc0 = 0, acc1 = 0, acc2 = 0, acc3 = 0, wsum = 0;
  int beg = rowptr[n], end = rowptr[n + 1];
  for (int base = beg; base < end; base += 64) {
    int cnt = end - base; if (cnt > 64) cnt = 64;
    int slot = tid >> 2, hh = tid & 3;
    if (slot < cnt) {
      int s = csr[base + slot];
      if (hh == 0) sl[slot] = s;
      float e = al[(size_t)s * 8 + hh] + al[(size_t)n * 8 + 4 + hh];
      wl[slot * 4 + hh] = __expf(lrelu(e));
    }
    __syncthreads();
    for (int j = 0; j < cnt; j++) {
      float wv = wl[j * 4 + h];
      int s = sl[j];
      ushort4 hv = *(const ushort4*)(h_body + (size_t)s * DB + c0);
      acc0 += wv * bf2f(hv.x); acc1 += wv * bf2f(hv.y);
      acc2 += wv * bf2f(hv.z); acc3 += wv * bf2f(hv.w);
      wsum += wv;
    }
    __syncthreads();
  }
  float inv = 1.f / (wsum + 1e-16f);
  ushort4 xf = *(const ushort4*)(xfc + (size_t)n * DB + c0);
  ushort4 o;
  o.x = f2bf(eluf(acc0 * inv + bb[c0 + 0] + bf2f(xf.x) + bfc[c0 + 0]));
  o.y = f2bf(eluf(acc1 * inv + bb[c0 + 1] + bf2f(xf.y) + bfc[c0 + 1]));
  o.z = f2bf(eluf(acc2 * inv + bb[c0 + 2] + bf2f(xf.z) + bfc[c0 + 2]));
  o.w = f2bf(eluf(acc3 * inv + bb[c0 + 3] + bf2f(xf.w) + bfc[c0 + 3]));
  *(ushort4*)(x1b + (size_t)n * DB + c0) = o;
}

// ---- per-chunk: transpose+convert weights -> Wt[g][512][1024] bf16 (B^T) ----
__global__ __launch_bounds__(256) void k_trans_w(const float* __restrict__ Wh, const float* __restrict__ W1,
                                                 u16* __restrict__ Wt, int t0) {
  __shared__ float tile[64][65];
  int t = t0 + blockIdx.z;
  int k0 = blockIdx.x * 64, n0 = blockIdx.y * 64;
  const float* Wsrc = (n0 < 256) ? (Wh + (size_t)t * 1024 * 256 + n0)
                                 : (W1 + (size_t)t * 1024 * 256 + (n0 - 256));
  int tid = threadIdx.x;
  for (int i = tid; i < 4096; i += 256) {
    int kr = i >> 6, nc = i & 63;
    tile[kr][nc] = Wsrc[(size_t)(k0 + kr) * 256 + nc];
  }
  __syncthreads();
  u16* dst = Wt + ((size_t)blockIdx.z * 512 + n0) * 1024 + k0;
  for (int i = tid; i < 4096; i += 256) {
    int nr = i >> 6, kc = i & 63;
    dst[(size_t)nr * 1024 + kc] = f2bf(tile[kc][nr]);
  }
}

// ---- bf16 MFMA GEMM, 128x256 tile, 512 threads (8 waves, 2m x 4n), BK=32 ----
// Best-known (r13): pre-barrier ds_read pipeline with ring-3 LDS (72 KB ->
// 2 blocks/CU) and ONE barrier per K-step. XCD z-pair-major job ordering
// (r10) + slot-rotation swizzle (r6, 0 bank conflicts). UNCHANGED this round.
__global__ __launch_bounds__(512, 4) void k_task_gemm(const u16* __restrict__ x1b, const u16* __restrict__ Wt,
                                                      u16* __restrict__ HT, int Gc, int q) {
  __shared__ alignas(16) u16 As[3][4096];   // 3 slots x A[128][32]  (24 KB)
  __shared__ alignas(16) u16 Bs[3][8192];   // 3 slots x B[256][32]  (48 KB)
  int zp = (Gc + 1) / 2;
  int jid = (blockIdx.x & 7) * q + (blockIdx.x >> 3);
  if (jid >= 158 * zp) return;
  int zpair = jid / 158;
  int rj = jid - zpair * 158;
  int bm = rj >> 1, bn = rj & 1;
  int tid = threadIdx.x;
  int sRow = tid >> 2, sQ = tid & 3;        // 128 rows x 4 granules of 8 u16 (16B)
  int sA = (sQ + (sRow >> 1)) & 3;          // rotated source 16B slot
  int m0 = bm * 128;
  int r0 = m0 + sRow; if (r0 > NN - 1) r0 = NN - 1;
  const u16* Ag = x1b + (size_t)r0 * 1024 + sA * 8;
  const u16* BgBase = Wt + ((size_t)(bn * 256) + sRow) * 1024 + sA * 8;
  int wv = tid >> 6, lane = tid & 63;
  int wm = wv >> 2, wn = wv & 3;
  // reader: logical slot s0=(lane>>4) of row r lives at LDS slot (s0-(r>>1))&3
  int qr = ((lane >> 4) - ((lane & 15) >> 1)) & 3;
  int fragOff = (lane & 15) * 32 + qr * 8;
  int AfO = (wm * 64) * 32 + fragOff;
  int BfO = (wn * 64) * 32 + fragOff;

  int zbeg = zpair * 2;
  int zend = zbeg + 2; if (zend > Gc) zend = Gc;
  for (int z = zbeg; z < zend; z++) {
    const u16* Bg0 = BgBase + (size_t)z * 524288;
    const u16* Bg1 = Bg0 + 131072;          // +128 n rows
    f32x4 acc[4][4];
    #pragma unroll
    for (int a = 0; a < 4; a++)
      #pragma unroll
      for (int b = 0; b < 4; b++) acc[a][b] = (f32x4){0.f, 0.f, 0.f, 0.f};

#define STAGE(kt_, slot_)                              \
    do {                                               \
      int _k = (kt_) * 32;                             \
      gload16(Ag + _k, &As[slot_][tid * 8]);           \
      gload16(Bg0 + _k, &Bs[slot_][tid * 8]);          \
      gload16(Bg1 + _k, &Bs[slot_][4096 + tid * 8]);   \
    } while (0)

    // prologue: stage kt 0,1 into slots 0,1 (6 loads/thread in flight)
    STAGE(0, 0);
    STAGE(1, 1);
    asm volatile("s_waitcnt vmcnt(3)" ::: "memory");   // slot 0 retired (slot 1 in flight)
    __builtin_amdgcn_s_barrier();                      // publish slot 0
    __builtin_amdgcn_sched_barrier(0);

    int scur = 0, stgt = 2;   // slot of kt, slot of kt+2
    for (int kt = 0; kt < 32; kt++) {
      // (1) pre-barrier ds_read of slot[kt] (published at previous barrier)
      const u16* Ac = &As[0][0] + scur * 4096 + AfO;
      const u16* Bc = &Bs[0][0] + scur * 8192 + BfO;
      short8 af[4], bfr[4];
      #pragma unroll
      for (int a = 0; a < 4; a++) af[a] = *(const short8*)(Ac + a * 512);
      #pragma unroll
      for (int b = 0; b < 4; b++) bfr[b] = *(const short8*)(Bc + b * 512);
      // (2) stage kt+2 into slot[(kt+2)%3] (== slot of kt-1; readers retired)
      if (kt + 2 < 32) STAGE(kt + 2, stgt);
      // (3) counted drain: retire slot[kt+1]'s loads; kt+2's stay in flight
      if (kt < 30) asm volatile("s_waitcnt vmcnt(3)" ::: "memory");
      else         asm volatile("s_waitcnt vmcnt(0)" ::: "memory");
      // (4) my frag reads complete BEFORE the barrier (race-freedom proof)
      asm volatile("s_waitcnt lgkmcnt(0)" ::: "memory");
      __builtin_amdgcn_sched_barrier(0);
      // (5) single barrier: publishes slot[kt+1] for next step's reads
      __builtin_amdgcn_s_barrier();
      __builtin_amdgcn_sched_barrier(0);
      // (6) MFMA on register-resident frags
      __builtin_amdgcn_s_setprio(1);
      #pragma unroll
      for (int a = 0; a < 4; a++)
        #pragma unroll
        for (int b = 0; b < 4; b++)
          acc[a][b] = __builtin_amdgcn_mfma_f32_16x16x32_bf16(af[a], bfr[b], acc[a][b], 0, 0, 0);
      __builtin_amdgcn_s_setprio(0);
      __builtin_amdgcn_sched_barrier(0);
      int t1 = scur + 1; scur = (t1 == 3) ? 0 : t1;
      int t2 = stgt + 1; stgt = (t2 == 3) ? 0 : t2;
    }
#undef STAGE
    u16* Hb = HT + (size_t)z * NN * 512;
    #pragma unroll
    for (int a = 0; a < 4; a++) {
      int rbase = m0 + wm * 64 + a * 16 + (lane >> 4) * 4;
      #pragma unroll
      for (int b = 0; b < 4; b++) {
        int col = bn * 256 + wn * 64 + b * 16 + (lane & 15);
        #pragma unroll
        for (int r = 0; r < 4; r++) {
          int row = rbase + r;
          if (row < NN) Hb[(size_t)row * 512 + col] = f2bf(acc[a][b][r]);
        }
      }
    }
    __syncthreads();  // full drain (incl. C-stores) before next task's prologue
  }
}

// ---- attention logits: 4 nodes per 256-thread block (wave per node) ----
__global__ __launch_bounds__(256) void k_task_al(const u16* __restrict__ HT, const float* __restrict__ ash,
                                                 const float* __restrict__ adh, float* __restrict__ ALt, int t0) {
  int l = threadIdx.x & 63;
  int n = blockIdx.x * 4 + (threadIdx.x >> 6);
  int g = blockIdx.y;
  int t = t0 + g;
  const u16* row = HT + ((size_t)g * NN + n) * 512 + l * 4;
  ushort4 v = *(const ushort4*)row;
  int h = l >> 4, cl = (l * 4) & 63;
  const float* ap = ash + ((size_t)t * 4 + h) * 64 + cl;
  const float* dp = adh + ((size_t)t * 4 + h) * 64 + cl;
  float f0 = bf2f(v.x), f1 = bf2f(v.y), f2 = bf2f(v.z), f3 = bf2f(v.w);
  float ss = f0 * ap[0] + f1 * ap[1] + f2 * ap[2] + f3 * ap[3];
  float sd = f0 * dp[0] + f1 * dp[1] + f2 * dp[2] + f3 * dp[3];
  #pragma unroll
  for (int o = 1; o < 16; o <<= 1) { ss += __shfl_xor(ss, o); sd += __shfl_xor(sd, o); }
  if ((l & 15) == 0) {
    float* dst = ALt + ((size_t)g * NN + n) * 8;
    dst[h] = ss; dst[4 + h] = sd;
  }
}

// ---- fused gather + softmax-normalize + elu + (256->2) projection ----
// 4 nodes per 256-thread block; each WAVE owns one node with a private LDS
// slice. Wave-local wl/sl communication needs only lgkmcnt(0) (same-wave DS
// visibility), not __syncthreads -- removes ~2 barriers per 64-edge chunk.
__global__ __launch_bounds__(256) void k_task_agg_out(const u16* __restrict__ HT, const float* __restrict__ ALt,
                                                      const int* __restrict__ rowptr, const int* __restrict__ csr,
                                                      const float* __restrict__ bh, const float* __restrict__ b1,
                                                      const float* __restrict__ W2, const float* __restrict__ b2,
                                                      float* __restrict__ out, int t0) {
  __shared__ float wl[4][256];
  __shared__ int sl[4][64];
  int wsl = threadIdx.x >> 6, l = threadIdx.x & 63;
  int n = blockIdx.x * 4 + wsl;
  int g = blockIdx.y;
  int t = t0 + g;
  int c0 = l * 4, h = l >> 4;
  const u16* Hb = HT + (size_t)g * NN * 512;
  const float* ALg = ALt + (size_t)g * NN * 8;
  float ad0 = ALg[(size_t)n * 8 + 4], ad1 = ALg[(size_t)n * 8 + 5];
  float ad2 = ALg[(size_t)n * 8 + 6], ad3 = ALg[(size_t)n * 8 + 7];
  float acc0 = 0, acc1 = 0, acc2 = 0, acc3 = 0, wsum = 0;
  int beg = rowptr[n], end = rowptr[n + 1];
  for (int base = beg; base < end; base += 64) {
    int cnt = end - base; if (cnt > 64) cnt = 64;
    if (l < cnt) {
      int s = csr[base + l];
      sl[wsl][l] = s;
      const float* alsp = ALg + (size_t)s * 8;
      wl[wsl][l * 4 + 0] = __expf(lrelu(alsp[0] + ad0));
      wl[wsl][l * 4 + 1] = __expf(lrelu(alsp[1] + ad1));
      wl[wsl][l * 4 + 2] = __expf(lrelu(alsp[2] + ad2));
      wl[wsl][l * 4 + 3] = __expf(lrelu(alsp[3] + ad3));
    }
    asm volatile("s_waitcnt lgkmcnt(0)" ::: "memory");  // wave-local publish
    __builtin_amdgcn_sched_barrier(0);
    for (int j = 0; j < cnt; j++) {
      float wv = wl[wsl][j * 4 + h];
      int s = sl[wsl][j];
      ushort4 hv = *(const ushort4*)(Hb + (size_t)s * 512 + c0);
      acc0 += wv * bf2f(hv.x); acc1 += wv * bf2f(hv.y);
      acc2 += wv * bf2f(hv.z); acc3 += wv * bf2f(hv.w);
      wsum += wv;
    }
    asm volatile("s_waitcnt lgkmcnt(0)" ::: "memory");  // reads done before next overwrite
    __builtin_amdgcn_sched_barrier(0);
  }
  float inv = 1.f / (wsum + 1e-16f);
  ushort4 fc = *(const ushort4*)(Hb + (size_t)n * 512 + 256 + c0);
  const float* bhp = bh + (size_t)t * 256 + c0;
  const float* b1p = b1 + (size_t)t * 256 + c0;
  const float* w2p = W2 + ((size_t)t * 256 + c0) * 2;
  float o0 = 0, o1 = 0, xv;
  xv = eluf(acc0 * inv + bhp[0] + bf2f(fc.x) + b1p[0]); o0 += xv * w2p[0]; o1 += xv * w2p[1];
  xv = eluf(acc1 * inv + bhp[1] + bf2f(fc.y) + b1p[1]); o0 += xv * w2p[2]; o1 += xv * w2p[3];
  xv = eluf(acc2 * inv + bhp[2] + bf2f(fc.z) + b1p[2]); o0 += xv * w2p[4]; o1 += xv * w2p[5];
  xv = eluf(acc3 * inv + bhp[3] + bf2f(fc.w) + b1p[3]); o0 += xv * w2p[6]; o1 += xv * w2p[7];
  #pragma unroll
  for (int o = 1; o < 64; o <<= 1) { o0 += __shfl_xor(o0, o); o1 += __shfl_xor(o1, o); }
  if (l == 0) {
    float* op = out + ((size_t)t * NN + n) * 2;
    op[0] = o0 + b2[t * 2];
    op[1] = o1 + b2[t * 2 + 1];
  }
}

extern "C" void kernel_launch(void* const* d_in, const int* in_sizes, int n_in,
                              void* d_out, int out_size, void* d_ws, size_t ws_size,
                              hipStream_t stream) {
  const float* x   = (const float*)d_in[0];
  const int*   ei  = (const int*)  d_in[1];
  const float* Wb  = (const float*)d_in[2];
  const float* asb = (const float*)d_in[3];
  const float* adb = (const float*)d_in[4];
  const float* bb  = (const float*)d_in[5];
  const float* Wfc = (const float*)d_in[6];
  const float* bfc = (const float*)d_in[7];
  const float* Wh  = (const float*)d_in[8];
  const float* ash = (const float*)d_in[9];
  const float* adh = (const float*)d_in[10];
  const float* bh  = (const float*)d_in[11];
  const float* W1  = (const float*)d_in[12];
  const float* b1  = (const float*)d_in[13];
  const float* W2  = (const float*)d_in[14];
  const float* b2  = (const float*)d_in[15];
  float* out = (float*)d_out;

  char* w = (char*)d_ws;
  size_t off = 0;
  auto take = [&](size_t b) { size_t o = off; off = (off + b + 255) & ~(size_t)255; return o; };
  u16*   x1b    = (u16*)  (w + take((size_t)NN * DB * 2));       // 20.48 MB
  float* albody = (float*)(w + take((size_t)NN * 8 * 4));        // 0.32 MB
  int*   flag   = (int*)  (w + take(4 + NN * 4 + NN * 4));       // [flag][deg][fill]
  int*   deg    = flag + 1;
  int*   fill   = deg + NN;
  int*   rowptr = (int*)  (w + take((NN + 1) * 4));
  int*   csr    = (int*)  (w + take((size_t)ET * 4));
  size_t Rbase = off;
  // body phase buffers (bf16), aliased with per-task buffers below
  u16* h_body = (u16*)(w + Rbase);
  u16* xfc    = h_body + (size_t)NN * DB;
  const size_t perTask = 1048576 + 10240000 + 320000;            // Wt + HT + AL (bytes, 256-aligned)
  size_t avail = ws_size > Rbase ? ws_size - Rbase : 0;
  int G = (int)(avail / perTask);
  if (G < 1) G = 1;
  if (G > NT) G = NT;
  u16*   Wt  = (u16*)(w + Rbase);
  u16*   HT  = Wt + (size_t)G * 524288;
  float* ALt = (float*)(HT + (size_t)G * 5120000);

  hipMemsetAsync(flag, 0, 4 + NN * 4 + NN * 4, stream);
  k_detect<<<1, 256, 0, stream>>>(ei, flag);
  k_deg<<<(ET + 255) / 256, 256, 0, stream>>>(ei, flag, deg);
  k_scan<<<1, 256, 0, stream>>>(deg, rowptr);
  k_fill<<<(ET + 255) / 256, 256, 0, stream>>>(ei, flag, rowptr, fill, csr);
  k_body_gemm<<<dim3(313, 8), 256, 0, stream>>>(x, Wb, Wfc, h_body, xfc);
  k_body_al<<<NN, 64, 0, stream>>>(h_body, asb, adb, albody);
  k_body_agg<<<NN, 256, 0, stream>>>(h_body, xfc, albody, rowptr, csr, bb, bfc, x1b);

  for (int t0 = 0; t0 < NT; t0 += G) {
    int Gc = NT - t0; if (Gc > G) Gc = G;
    int zp = (Gc + 1) / 2;
    int jobs = 158 * zp;
    int q = (jobs + 7) / 8;
    k_trans_w<<<dim3(16, 8, Gc), 256, 0, stream>>>(Wh, W1, Wt, t0);
    k_task_gemm<<<8 * q, 512, 0, stream>>>(x1b, Wt, HT, Gc, q);
    k_task_al<<<dim3(NN / 4, Gc), 256, 0, stream>>>(HT, ash, adh, ALt, t0);
    k_task_agg_out<<<dim3(NN / 4, Gc), 256, 0, stream>>>(HT, ALt, rowptr, csr, bh, b1, W2, b2, out, t0);
  }
}

// Round 17
// 3280.939 us; speedup vs baseline: 1.0564x; 1.0564x over previous
//
#include <hip/hip_runtime.h>

typedef unsigned short u16;
typedef unsigned int u32;
typedef __attribute__((ext_vector_type(8))) short short8;
typedef __attribute__((ext_vector_type(4))) float f32x4;

#define NN 10000
#define NE 160000
#define ET 170000
#define FI 50
#define DB 1024
#define NT 121

static __device__ __forceinline__ float bf2f(u16 b) { return __uint_as_float(((u32)b) << 16); }
static __device__ __forceinline__ u16 f2bf(float f) {
  u32 u = __float_as_uint(f);
  u += 0x7FFFu + ((u >> 16) & 1u);
  return (u16)(u >> 16);
}
static __device__ __forceinline__ float eluf(float x) { return x > 0.f ? x : __expf(x) - 1.f; }
static __device__ __forceinline__ float lrelu(float x) { return x > 0.f ? x : 0.2f * x; }

__device__ __forceinline__ void gload16(const void* g, void* l) {
  __builtin_amdgcn_global_load_lds((const __attribute__((address_space(1))) u32*)g,
                                   (__attribute__((address_space(3))) u32*)l, 16, 0, 0);
}

// ---- edge dtype detection: int64 data has all-zero odd 32-bit words ----
__global__ __launch_bounds__(256) void k_detect(const int* __restrict__ ei, int* flag) {
  int any = 0;
  for (int i = threadIdx.x; i < NE; i += 256) any |= ei[2 * i + 1];
  if (any) flag[0] = 1;  // 1 => int32 layout
}

__global__ __launch_bounds__(256) void k_deg(const int* __restrict__ ei, const int* __restrict__ flag,
                                             int* deg) {
  int e = blockIdx.x * 256 + threadIdx.x;
  if (e >= ET) return;
  int is32 = flag[0];
  int d = (e < NE) ? (is32 ? ei[NE + e] : ei[2 * (NE + e)]) : (e - NE);
  atomicAdd(&deg[d], 1);
}

__global__ __launch_bounds__(256) void k_scan(const int* __restrict__ deg, int* __restrict__ rowptr) {
  __shared__ int ps[256];
  int tid = threadIdx.x;
  int s = 0;
  for (int i = 0; i < 40; i++) { int idx = tid * 40 + i; if (idx < NN) s += deg[idx]; }
  ps[tid] = s;
  __syncthreads();
  if (tid == 0) {
    int run = 0;
    for (int i = 0; i < 256; i++) { int v = ps[i]; ps[i] = run; run += v; }
    rowptr[NN] = run;
  }
  __syncthreads();
  int run = ps[tid];
  for (int i = 0; i < 40; i++) {
    int idx = tid * 40 + i;
    if (idx < NN) { rowptr[idx] = run; run += deg[idx]; }
  }
}

__global__ __launch_bounds__(256) void k_fill(const int* __restrict__ ei, const int* __restrict__ flag,
                                              const int* __restrict__ rowptr, int* fill, int* csr) {
  int e = blockIdx.x * 256 + threadIdx.x;
  if (e >= ET) return;
  int is32 = flag[0];
  int s, d;
  if (e < NE) { s = is32 ? ei[e] : ei[2 * e]; d = is32 ? ei[NE + e] : ei[2 * (NE + e)]; }
  else { s = d = e - NE; }
  int pos = atomicAdd(&fill[d], 1);
  csr[rowptr[d] + pos] = s;
}

// ---- body: h_body = x@W_body, xfc = x@Wfc (f32 compute, bf16 store, K=50) ----
__global__ __launch_bounds__(256) void k_body_gemm(const float* __restrict__ x, const float* __restrict__ Wb,
                                                   const float* __restrict__ Wfc,
                                                   u16* __restrict__ h_body, u16* __restrict__ xfc) {
  __shared__ float xs[32][52];
  int tid = threadIdx.x;
  int m0 = blockIdx.x * 32;
  for (int i = tid; i < 32 * FI; i += 256) {
    int r = i / FI, c = i - r * FI;
    int row = m0 + r; if (row > NN - 1) row = NN - 1;
    xs[r][c] = x[(size_t)row * FI + c];
  }
  __syncthreads();
  int col = blockIdx.y * 256 + tid;
  const float* Wp; u16* op;
  if (col < DB) { Wp = Wb + col; op = h_body + col; }
  else { Wp = Wfc + (col - DB); op = xfc + (col - DB); }
  float acc[32];
  #pragma unroll
  for (int m = 0; m < 32; m++) acc[m] = 0.f;
  for (int k = 0; k < FI; k++) {
    float wv = Wp[(size_t)k * DB];
    #pragma unroll
    for (int m = 0; m < 32; m++) acc[m] += xs[m][k] * wv;
  }
  #pragma unroll
  for (int m = 0; m < 32; m++) {
    int row = m0 + m;
    if (row < NN) op[(size_t)row * DB] = f2bf(acc[m]);
  }
}

__global__ __launch_bounds__(64) void k_body_al(const u16* __restrict__ h_body, const float* __restrict__ as,
                                                const float* __restrict__ ad, float* __restrict__ al) {
  int n = blockIdx.x, l = threadIdx.x;
  const u16* hr = h_body + (size_t)n * DB + l * 16;
  const float* ap = as + l * 16;
  const float* dp = ad + l * 16;
  float ss = 0.f, sd = 0.f;
  #pragma unroll
  for (int i = 0; i < 16; i++) { float hv = bf2f(hr[i]); ss += hv * ap[i]; sd += hv * dp[i]; }
  #pragma unroll
  for (int o = 1; o < 16; o <<= 1) { ss += __shfl_xor(ss, o); sd += __shfl_xor(sd, o); }
  if ((l & 15) == 0) { int h = l >> 4; al[(size_t)n * 8 + h] = ss; al[(size_t)n * 8 + 4 + h] = sd; }
}

__global__ __launch_bounds__(256) void k_body_agg(const u16* __restrict__ h_body, const u16* __restrict__ xfc,
                                                  const float* __restrict__ al, const int* __restrict__ rowptr,
                                                  const int* __restrict__ csr, const float* __restrict__ bb,
                                                  const float* __restrict__ bfc, u16* __restrict__ x1b) {
  __shared__ float wl[256];
  __shared__ int sl[64];
  int n = blockIdx.x, tid = threadIdx.x;
  int c0 = tid * 4, h = tid >> 6;
  float acc0 = 0, acc1 = 0, acc2 = 0, acc3 = 0, wsum = 0;
  int beg = rowptr[n], end = rowptr[n + 1];
  for (int base = beg; base < end; base += 64) {
    int cnt = end - base; if (cnt > 64) cnt = 64;
    int slot = tid >> 2, hh = tid & 3;
    if (slot < cnt) {
      int s = csr[base + slot];
      if (hh == 0) sl[slot] = s;
      float e = al[(size_t)s * 8 + hh] + al[(size_t)n * 8 + 4 + hh];
      wl[slot * 4 + hh] = __expf(lrelu(e));
    }
    __syncthreads();
    for (int j = 0; j < cnt; j++) {
      float wv = wl[j * 4 + h];
      int s = sl[j];
      ushort4 hv = *(const ushort4*)(h_body + (size_t)s * DB + c0);
      acc0 += wv * bf2f(hv.x); acc1 += wv * bf2f(hv.y);
      acc2 += wv * bf2f(hv.z); acc3 += wv * bf2f(hv.w);
      wsum += wv;
    }
    __syncthreads();
  }
  float inv = 1.f / (wsum + 1e-16f);
  ushort4 xf = *(const ushort4*)(xfc + (size_t)n * DB + c0);
  ushort4 o;
  o.x = f2bf(eluf(acc0 * inv + bb[c0 + 0] + bf2f(xf.x) + bfc[c0 + 0]));
  o.y = f2bf(eluf(acc1 * inv + bb[c0 + 1] + bf2f(xf.y) + bfc[c0 + 1]));
  o.z = f2bf(eluf(acc2 * inv + bb[c0 + 2] + bf2f(xf.z) + bfc[c0 + 2]));
  o.w = f2bf(eluf(acc3 * inv + bb[c0 + 3] + bf2f(xf.w) + bfc[c0 + 3]));
  *(ushort4*)(x1b + (size_t)n * DB + c0) = o;
}

// ---- per-chunk: transpose+convert weights -> Wt[g][512][1024] bf16 (B^T) ----
__global__ __launch_bounds__(256) void k_trans_w(const float* __restrict__ Wh, const float* __restrict__ W1,
                                                 u16* __restrict__ Wt, int t0) {
  __shared__ float tile[64][65];
  int t = t0 + blockIdx.z;
  int k0 = blockIdx.x * 64, n0 = blockIdx.y * 64;
  const float* Wsrc = (n0 < 256) ? (Wh + (size_t)t * 1024 * 256 + n0)
                                 : (W1 + (size_t)t * 1024 * 256 + (n0 - 256));
  int tid = threadIdx.x;
  for (int i = tid; i < 4096; i += 256) {
    int kr = i >> 6, nc = i & 63;
    tile[kr][nc] = Wsrc[(size_t)(k0 + kr) * 256 + nc];
  }
  __syncthreads();
  u16* dst = Wt + ((size_t)blockIdx.z * 512 + n0) * 1024 + k0;
  for (int i = tid; i < 4096; i += 256) {
    int nr = i >> 6, kc = i & 63;
    dst[(size_t)nr * 1024 + kc] = f2bf(tile[kc][nr]);
  }
}

// ---- bf16 MFMA GEMM, 128x256 tile, 512 threads (8 waves, 2m x 4n), BK=32 ----
// FINAL (r13 best-known, 3285 us): pre-barrier ds_read pipeline with ring-3
// LDS (72 KB -> 2 blocks/CU) and ONE barrier per K-step. Per step kt:
//   (1) 8 ds_read slot[kt%3] (published by PREVIOUS step's barrier)
//   (2) STAGE(kt+2 -> slot[(kt+2)%3])   [slot == kt-1's; readers retired at
//       their pre-barrier lgkmcnt(0) -- race-free]
//   (3) vmcnt(3): retire slot[kt+1]'s loads (kt+2's 3 stay in flight)
//   (4) lgkmcnt(0) BEFORE the barrier
//   (5) s_barrier (publishes slot[kt+1] for next step's pre-barrier reads)
//   (6) setprio(1) + 16 MFMA
// XCD z-pair-major job ordering (r10) + slot-rotation swizzle (r6, 0 bank
// conflicts). Session ledger: AL-fusion (r9, r14), 1-barrier-post-read (r8),
// ring-4 256^2 (r7), frag-dbuf (r11), tail batching (r16) all regressed and
// were reverted; r5/r10/r13 are the wins this config embodies.
__global__ __launch_bounds__(512, 4) void k_task_gemm(const u16* __restrict__ x1b, const u16* __restrict__ Wt,
                                                      u16* __restrict__ HT, int Gc, int q) {
  __shared__ alignas(16) u16 As[3][4096];   // 3 slots x A[128][32]  (24 KB)
  __shared__ alignas(16) u16 Bs[3][8192];   // 3 slots x B[256][32]  (48 KB)
  int zp = (Gc + 1) / 2;
  int jid = (blockIdx.x & 7) * q + (blockIdx.x >> 3);
  if (jid >= 158 * zp) return;
  int zpair = jid / 158;
  int rj = jid - zpair * 158;
  int bm = rj >> 1, bn = rj & 1;
  int tid = threadIdx.x;
  int sRow = tid >> 2, sQ = tid & 3;        // 128 rows x 4 granules of 8 u16 (16B)
  int sA = (sQ + (sRow >> 1)) & 3;          // rotated source 16B slot
  int m0 = bm * 128;
  int r0 = m0 + sRow; if (r0 > NN - 1) r0 = NN - 1;
  const u16* Ag = x1b + (size_t)r0 * 1024 + sA * 8;
  const u16* BgBase = Wt + ((size_t)(bn * 256) + sRow) * 1024 + sA * 8;
  int wv = tid >> 6, lane = tid & 63;
  int wm = wv >> 2, wn = wv & 3;
  // reader: logical slot s0=(lane>>4) of row r lives at LDS slot (s0-(r>>1))&3
  int qr = ((lane >> 4) - ((lane & 15) >> 1)) & 3;
  int fragOff = (lane & 15) * 32 + qr * 8;
  int AfO = (wm * 64) * 32 + fragOff;
  int BfO = (wn * 64) * 32 + fragOff;

  int zbeg = zpair * 2;
  int zend = zbeg + 2; if (zend > Gc) zend = Gc;
  for (int z = zbeg; z < zend; z++) {
    const u16* Bg0 = BgBase + (size_t)z * 524288;
    const u16* Bg1 = Bg0 + 131072;          // +128 n rows
    f32x4 acc[4][4];
    #pragma unroll
    for (int a = 0; a < 4; a++)
      #pragma unroll
      for (int b = 0; b < 4; b++) acc[a][b] = (f32x4){0.f, 0.f, 0.f, 0.f};

#define STAGE(kt_, slot_)                              \
    do {                                               \
      int _k = (kt_) * 32;                             \
      gload16(Ag + _k, &As[slot_][tid * 8]);           \
      gload16(Bg0 + _k, &Bs[slot_][tid * 8]);          \
      gload16(Bg1 + _k, &Bs[slot_][4096 + tid * 8]);   \
    } while (0)

    // prologue: stage kt 0,1 into slots 0,1 (6 loads/thread in flight)
    STAGE(0, 0);
    STAGE(1, 1);
    asm volatile("s_waitcnt vmcnt(3)" ::: "memory");   // slot 0 retired (slot 1 in flight)
    __builtin_amdgcn_s_barrier();                      // publish slot 0
    __builtin_amdgcn_sched_barrier(0);

    int scur = 0, stgt = 2;   // slot of kt, slot of kt+2
    for (int kt = 0; kt < 32; kt++) {
      // (1) pre-barrier ds_read of slot[kt] (published at previous barrier)
      const u16* Ac = &As[0][0] + scur * 4096 + AfO;
      const u16* Bc = &Bs[0][0] + scur * 8192 + BfO;
      short8 af[4], bfr[4];
      #pragma unroll
      for (int a = 0; a < 4; a++) af[a] = *(const short8*)(Ac + a * 512);
      #pragma unroll
      for (int b = 0; b < 4; b++) bfr[b] = *(const short8*)(Bc + b * 512);
      // (2) stage kt+2 into slot[(kt+2)%3] (== slot of kt-1; readers retired)
      if (kt + 2 < 32) STAGE(kt + 2, stgt);
      // (3) counted drain: retire slot[kt+1]'s loads; kt+2's stay in flight
      if (kt < 30) asm volatile("s_waitcnt vmcnt(3)" ::: "memory");
      else         asm volatile("s_waitcnt vmcnt(0)" ::: "memory");
      // (4) my frag reads complete BEFORE the barrier (race-freedom proof)
      asm volatile("s_waitcnt lgkmcnt(0)" ::: "memory");
      __builtin_amdgcn_sched_barrier(0);
      // (5) single barrier: publishes slot[kt+1] for next step's reads
      __builtin_amdgcn_s_barrier();
      __builtin_amdgcn_sched_barrier(0);
      // (6) MFMA on register-resident frags
      __builtin_amdgcn_s_setprio(1);
      #pragma unroll
      for (int a = 0; a < 4; a++)
        #pragma unroll
        for (int b = 0; b < 4; b++)
          acc[a][b] = __builtin_amdgcn_mfma_f32_16x16x32_bf16(af[a], bfr[b], acc[a][b], 0, 0, 0);
      __builtin_amdgcn_s_setprio(0);
      __builtin_amdgcn_sched_barrier(0);
      int t1 = scur + 1; scur = (t1 == 3) ? 0 : t1;
      int t2 = stgt + 1; stgt = (t2 == 3) ? 0 : t2;
    }
#undef STAGE
    u16* Hb = HT + (size_t)z * NN * 512;
    #pragma unroll
    for (int a = 0; a < 4; a++) {
      int rbase = m0 + wm * 64 + a * 16 + (lane >> 4) * 4;
      #pragma unroll
      for (int b = 0; b < 4; b++) {
        int col = bn * 256 + wn * 64 + b * 16 + (lane & 15);
        #pragma unroll
        for (int r = 0; r < 4; r++) {
          int row = rbase + r;
          if (row < NN) Hb[(size_t)row * 512 + col] = f2bf(acc[a][b][r]);
        }
      }
    }
    __syncthreads();  // full drain (incl. C-stores) before next task's prologue
  }
}

__global__ __launch_bounds__(64) void k_task_al(const u16* __restrict__ HT, const float* __restrict__ ash,
                                                const float* __restrict__ adh, float* __restrict__ ALt, int t0) {
  int n = blockIdx.x, g = blockIdx.y, l = threadIdx.x;
  int t = t0 + g;
  const u16* row = HT + ((size_t)g * NN + n) * 512 + l * 4;
  ushort4 v = *(const ushort4*)row;
  int h = l >> 4, cl = (l * 4) & 63;
  const float* ap = ash + ((size_t)t * 4 + h) * 64 + cl;
  const float* dp = adh + ((size_t)t * 4 + h) * 64 + cl;
  float f0 = bf2f(v.x), f1 = bf2f(v.y), f2 = bf2f(v.z), f3 = bf2f(v.w);
  float ss = f0 * ap[0] + f1 * ap[1] + f2 * ap[2] + f3 * ap[3];
  float sd = f0 * dp[0] + f1 * dp[1] + f2 * dp[2] + f3 * dp[3];
  #pragma unroll
  for (int o = 1; o < 16; o <<= 1) { ss += __shfl_xor(ss, o); sd += __shfl_xor(sd, o); }
  if ((l & 15) == 0) {
    float* dst = ALt + ((size_t)g * NN + n) * 8;
    dst[h] = ss; dst[4 + h] = sd;
  }
}

// ---- fused gather + softmax-normalize + elu + (256->2) projection ----
__global__ __launch_bounds__(64) void k_task_agg_out(const u16* __restrict__ HT, const float* __restrict__ ALt,
                                                     const int* __restrict__ rowptr, const int* __restrict__ csr,
                                                     const float* __restrict__ bh, const float* __restrict__ b1,
                                                     const float* __restrict__ W2, const float* __restrict__ b2,
                                                     float* __restrict__ out, int t0) {
  __shared__ float wl[256];
  __shared__ int sl[64];
  int n = blockIdx.x, g = blockIdx.y, l = threadIdx.x;
  int t = t0 + g;
  int c0 = l * 4, h = l >> 4;
  const u16* Hb = HT + (size_t)g * NN * 512;
  const float* ALg = ALt + (size_t)g * NN * 8;
  float ad0 = ALg[(size_t)n * 8 + 4], ad1 = ALg[(size_t)n * 8 + 5];
  float ad2 = ALg[(size_t)n * 8 + 6], ad3 = ALg[(size_t)n * 8 + 7];
  float acc0 = 0, acc1 = 0, acc2 = 0, acc3 = 0, wsum = 0;
  int beg = rowptr[n], end = rowptr[n + 1];
  for (int base = beg; base < end; base += 64) {
    int cnt = end - base; if (cnt > 64) cnt = 64;
    if (l < cnt) {
      int s = csr[base + l];
      sl[l] = s;
      const float* alsp = ALg + (size_t)s * 8;
      wl[l * 4 + 0] = __expf(lrelu(alsp[0] + ad0));
      wl[l * 4 + 1] = __expf(lrelu(alsp[1] + ad1));
      wl[l * 4 + 2] = __expf(lrelu(alsp[2] + ad2));
      wl[l * 4 + 3] = __expf(lrelu(alsp[3] + ad3));
    }
    __syncthreads();
    for (int j = 0; j < cnt; j++) {
      float wv = wl[j * 4 + h];
      int s = sl[j];
      ushort4 hv = *(const ushort4*)(Hb + (size_t)s * 512 + c0);
      acc0 += wv * bf2f(hv.x); acc1 += wv * bf2f(hv.y);
      acc2 += wv * bf2f(hv.z); acc3 += wv * bf2f(hv.w);
      wsum += wv;
    }
    __syncthreads();
  }
  float inv = 1.f / (wsum + 1e-16f);
  ushort4 fc = *(const ushort4*)(Hb + (size_t)n * 512 + 256 + c0);
  const float* bhp = bh + (size_t)t * 256 + c0;
  const float* b1p = b1 + (size_t)t * 256 + c0;
  const float* w2p = W2 + ((size_t)t * 256 + c0) * 2;
  float o0 = 0, o1 = 0, xv;
  xv = eluf(acc0 * inv + bhp[0] + bf2f(fc.x) + b1p[0]); o0 += xv * w2p[0]; o1 += xv * w2p[1];
  xv = eluf(acc1 * inv + bhp[1] + bf2f(fc.y) + b1p[1]); o0 += xv * w2p[2]; o1 += xv * w2p[3];
  xv = eluf(acc2 * inv + bhp[2] + bf2f(fc.z) + b1p[2]); o0 += xv * w2p[4]; o1 += xv * w2p[5];
  xv = eluf(acc3 * inv + bhp[3] + bf2f(fc.w) + b1p[3]); o0 += xv * w2p[6]; o1 += xv * w2p[7];
  #pragma unroll
  for (int o = 1; o < 64; o <<= 1) { o0 += __shfl_xor(o0, o); o1 += __shfl_xor(o1, o); }
  if (l == 0) {
    float* op = out + ((size_t)t * NN + n) * 2;
    op[0] = o0 + b2[t * 2];
    op[1] = o1 + b2[t * 2 + 1];
  }
}

extern "C" void kernel_launch(void* const* d_in, const int* in_sizes, int n_in,
                              void* d_out, int out_size, void* d_ws, size_t ws_size,
                              hipStream_t stream) {
  const float* x   = (const float*)d_in[0];
  const int*   ei  = (const int*)  d_in[1];
  const float* Wb  = (const float*)d_in[2];
  const float* asb = (const float*)d_in[3];
  const float* adb = (const float*)d_in[4];
  const float* bb  = (const float*)d_in[5];
  const float* Wfc = (const float*)d_in[6];
  const float* bfc = (const float*)d_in[7];
  const float* Wh  = (const float*)d_in[8];
  const float* ash = (const float*)d_in[9];
  const float* adh = (const float*)d_in[10];
  const float* bh  = (const float*)d_in[11];
  const float* W1  = (const float*)d_in[12];
  const float* b1  = (const float*)d_in[13];
  const float* W2  = (const float*)d_in[14];
  const float* b2  = (const float*)d_in[15];
  float* out = (float*)d_out;

  char* w = (char*)d_ws;
  size_t off = 0;
  auto take = [&](size_t b) { size_t o = off; off = (off + b + 255) & ~(size_t)255; return o; };
  u16*   x1b    = (u16*)  (w + take((size_t)NN * DB * 2));       // 20.48 MB
  float* albody = (float*)(w + take((size_t)NN * 8 * 4));        // 0.32 MB
  int*   flag   = (int*)  (w + take(4 + NN * 4 + NN * 4));       // [flag][deg][fill]
  int*   deg    = flag + 1;
  int*   fill   = deg + NN;
  int*   rowptr = (int*)  (w + take((NN + 1) * 4));
  int*   csr    = (int*)  (w + take((size_t)ET * 4));
  size_t Rbase = off;
  // body phase buffers (bf16), aliased with per-task buffers below
  u16* h_body = (u16*)(w + Rbase);
  u16* xfc    = h_body + (size_t)NN * DB;
  const size_t perTask = 1048576 + 10240000 + 320000;            // Wt + HT + AL (bytes, 256-aligned)
  size_t avail = ws_size > Rbase ? ws_size - Rbase : 0;
  int G = (int)(avail / perTask);
  if (G < 1) G = 1;
  if (G > NT) G = NT;
  u16*   Wt  = (u16*)(w + Rbase);
  u16*   HT  = Wt + (size_t)G * 524288;
  float* ALt = (float*)(HT + (size_t)G * 5120000);

  hipMemsetAsync(flag, 0, 4 + NN * 4 + NN * 4, stream);
  k_detect<<<1, 256, 0, stream>>>(ei, flag);
  k_deg<<<(ET + 255) / 256, 256, 0, stream>>>(ei, flag, deg);
  k_scan<<<1, 256, 0, stream>>>(deg, rowptr);
  k_fill<<<(ET + 255) / 256, 256, 0, stream>>>(ei, flag, rowptr, fill, csr);
  k_body_gemm<<<dim3(313, 8), 256, 0, stream>>>(x, Wb, Wfc, h_body, xfc);
  k_body_al<<<NN, 64, 0, stream>>>(h_body, asb, adb, albody);
  k_body_agg<<<NN, 256, 0, stream>>>(h_body, xfc, albody, rowptr, csr, bb, bfc, x1b);

  for (int t0 = 0; t0 < NT; t0 += G) {
    int Gc = NT - t0; if (Gc > G) Gc = G;
    int zp = (Gc + 1) / 2;
    int jobs = 158 * zp;
    int q = (jobs + 7) / 8;
    k_trans_w<<<dim3(16, 8, Gc), 256, 0, stream>>>(Wh, W1, Wt, t0);
    k_task_gemm<<<8 * q, 512, 0, stream>>>(x1b, Wt, HT, Gc, q);
    k_task_al<<<dim3(NN, Gc), 64, 0, stream>>>(HT, ash, adh, ALt, t0);
    k_task_agg_out<<<dim3(NN, Gc), 64, 0, stream>>>(HT, ALt, rowptr, csr, bh, b1, W2, b2, out, t0);
  }
}